// Round 1
// baseline (1038.169 us; speedup 1.0000x reference)
//
#include <hip/hip_runtime.h>
#include <hip/hip_bf16.h>

// BertSelfAttention: B=4, S=1024, HID=1024, H=16, D=64, MAXP=1024
// Round 1: correct fp32 baseline.
//   K1: fused QKV projection GEMM (64x64 tile, BK=16, 4x4 microtile, fp32)
//   K2: fused flash-style attention with Toeplitz relative-position band in LDS
// ws layout: Q at 0, K at 4M floats, V at 8M floats (16 MB each, 48 MB total)

#define BB 4
#define SS 1024
#define HHID 1024
#define HH 16
#define DD 64
#define EPSV 1e-8f

// ---------------------------------------------------------------------------
// K1: C[n,c] = sum_k X[n,k]*W[k,c] + bias[c], written head-split to [B,H,S,D]
// grid (64,16,3): z selects Q/K/V weight set.
__global__ __launch_bounds__(256) void qkv_gemm(
    const float* __restrict__ X,
    const float* __restrict__ Wq, const float* __restrict__ bq,
    const float* __restrict__ Wk, const float* __restrict__ bk,
    const float* __restrict__ Wv, const float* __restrict__ bv,
    float* __restrict__ qkv)
{
    __shared__ float As[16][68];  // As[kk][row], stride 68 keeps float4 reads 16B-aligned
    __shared__ float Bs[16][68];  // Bs[kk][col]

    const float* W;  const float* bias;  float* out;
    const int z = blockIdx.z;
    if (z == 0)      { W = Wq; bias = bq; out = qkv; }
    else if (z == 1) { W = Wk; bias = bk; out = qkv + 4 * 1024 * 1024; }
    else             { W = Wv; bias = bv; out = qkv + 8 * 1024 * 1024; }

    const int tid = threadIdx.x;
    const int tx = tid & 15, ty = tid >> 4;
    const int n0 = blockIdx.x * 64;
    const int c0 = blockIdx.y * 64;

    // staging assignments
    const int ar = tid >> 2;          // 0..63 (A row in tile)
    const int ac = (tid & 3) << 2;    // 0,4,8,12 (A col chunk)
    const int br = tid >> 4;          // 0..15 (B row in tile)
    const int bc = (tid & 15) << 2;   // 0..60 (B col chunk)

    const float* Xp = X + (n0 + ar) * HHID + ac;
    const float* Wp = W + br * HHID + c0 + bc;

    float acc[4][4] = {{0.f}};

    for (int k0 = 0; k0 < HHID; k0 += 16) {
        float4 a = *(const float4*)(Xp + k0);
        float4 bvec = *(const float4*)(Wp + (size_t)k0 * HHID);
        __syncthreads();
        As[ac + 0][ar] = a.x;
        As[ac + 1][ar] = a.y;
        As[ac + 2][ar] = a.z;
        As[ac + 3][ar] = a.w;
        *(float4*)&Bs[br][bc] = bvec;
        __syncthreads();
#pragma unroll
        for (int kk = 0; kk < 16; ++kk) {
            float4 av = *(const float4*)&As[kk][ty << 2];
            float4 bv = *(const float4*)&Bs[kk][tx << 2];
            float aa[4] = {av.x, av.y, av.z, av.w};
            float bb[4] = {bv.x, bv.y, bv.z, bv.w};
#pragma unroll
            for (int i = 0; i < 4; ++i)
#pragma unroll
                for (int j = 0; j < 4; ++j)
                    acc[i][j] += aa[i] * bb[j];
        }
    }

    // epilogue: add bias, scatter to [B,H,S,D]
    const int h = c0 >> 6;                       // whole block is one head slice
    float4 bias4 = *(const float4*)(bias + c0 + (tx << 2));
#pragma unroll
    for (int i = 0; i < 4; ++i) {
        const int n = n0 + (ty << 2) + i;
        const int b = n >> 10, s = n & 1023;
        float4 o;
        o.x = acc[i][0] + bias4.x;
        o.y = acc[i][1] + bias4.y;
        o.z = acc[i][2] + bias4.z;
        o.w = acc[i][3] + bias4.w;
        *(float4*)(out + (((size_t)(b * HH + h) * SS + s) * DD) + (tx << 2)) = o;
    }
}

// ---------------------------------------------------------------------------
// K2: fused attention. grid (S/32, B*H). 32 query rows per block.
// score(l,r) = q·(k_r + dist_emb[l-r+1023]) / 8 + amask[b,r]
// e = exp(score)*skim[b,r];  out = (Σ e·v) / (EPS + Σ e)
__global__ __launch_bounds__(256) void attn(
    const float* __restrict__ QKV,
    const float* __restrict__ amask,   // [B,S]
    const int*   __restrict__ skim,    // [B,S]
    const float* __restrict__ dist,    // [2047,64]
    float* __restrict__ out)           // [B,S,HID]
{
    __shared__ float Qs[32][68];   // pre-scaled by 1/8; stride 68 for aligned float4
    __shared__ float Ks[32][68];
    __shared__ float Ps[63][68];   // dist_emb band rows d0-31..d0+31
    __shared__ float Vs[32][65];   // scalar access, stride 65 conflict-free
    __shared__ float Es[32][33];
    __shared__ float lrun[32];

    const int tid = threadIdx.x;
    const int bh = blockIdx.y;         // b*16 + h
    const int b = bh >> 4;
    const int hh = bh & 15;
    const int l0 = blockIdx.x << 5;

    const float* Qg = QKV + ((size_t)bh * SS + l0) * DD;
    const float* Kg = QKV + 4 * 1024 * 1024 + (size_t)bh * SS * DD;
    const float* Vg = QKV + 8 * 1024 * 1024 + (size_t)bh * SS * DD;

    // load + pre-scale Q tile (32x64 = 512 float4 chunks)
    {
        int idx = tid;
#pragma unroll
        for (int p = 0; p < 2; ++p, idx += 256) {
            const int r = idx >> 4, c = (idx & 15) << 2;
            float4 q = *(const float4*)(Qg + r * DD + c);
            Qs[r][c + 0] = q.x * 0.125f;
            Qs[r][c + 1] = q.y * 0.125f;
            Qs[r][c + 2] = q.z * 0.125f;
            Qs[r][c + 3] = q.w * 0.125f;
        }
    }
    if (tid < 32) lrun[tid] = 0.f;

    const int j   = tid & 31;   // score phase: key column
    const int i4  = tid >> 5;   // score phase: row group 0..7
    const int dpv = tid & 63;   // PV phase: d
    const int i8  = tid >> 6;   // PV phase: row group 0..3
    float acc[8] = {0.f};

    for (int r0 = 0; r0 < SS; r0 += 32) {
        __syncthreads();
        // stage K, V tiles
        {
            int idx = tid;
#pragma unroll
            for (int p = 0; p < 2; ++p, idx += 256) {
                const int r = idx >> 4, c = (idx & 15) << 2;
                float4 kv = *(const float4*)(Kg + (r0 + r) * DD + c);
                Ks[r][c + 0] = kv.x; Ks[r][c + 1] = kv.y;
                Ks[r][c + 2] = kv.z; Ks[r][c + 3] = kv.w;
                float4 vv = *(const float4*)(Vg + (r0 + r) * DD + c);
                Vs[r][c + 0] = vv.x; Vs[r][c + 1] = vv.y;
                Vs[r][c + 2] = vv.z; Vs[r][c + 3] = vv.w;
            }
        }
        // stage dist_emb band: global rows (l0-r0+992) .. +62  (always in [0,2046])
        {
            const int d0b = l0 - r0 + 992;
            for (int idx = tid; idx < 63 * 16; idx += 256) {
                const int r = idx >> 4, c = (idx & 15) << 2;
                float4 pv = *(const float4*)(dist + (size_t)(d0b + r) * DD + c);
                Ps[r][c + 0] = pv.x; Ps[r][c + 1] = pv.y;
                Ps[r][c + 2] = pv.z; Ps[r][c + 3] = pv.w;
            }
        }
        __syncthreads();

        // scores: thread (i4,j) computes rows i4*4..i4*4+3 vs key j
        {
            float s[4] = {0.f, 0.f, 0.f, 0.f};
#pragma unroll
            for (int dc = 0; dc < DD; dc += 4) {
                float4 kv = *(const float4*)&Ks[j][dc];
#pragma unroll
                for (int ii = 0; ii < 4; ++ii) {
                    const int i = (i4 << 2) + ii;
                    float4 qv = *(const float4*)&Qs[i][dc];
                    float4 pv = *(const float4*)&Ps[i - j + 31][dc];
                    s[ii] += qv.x * (kv.x + pv.x) + qv.y * (kv.y + pv.y)
                           + qv.z * (kv.z + pv.z) + qv.w * (kv.w + pv.w);
                }
            }
            const float am = amask[b * SS + r0 + j];
            const float sk = (float)skim[b * SS + r0 + j];
#pragma unroll
            for (int ii = 0; ii < 4; ++ii)
                Es[(i4 << 2) + ii][j] = __expf(s[ii] + am) * sk;
        }
        __syncthreads();

        // running row sums (threads 0..31) — read only after final barrier
        if (tid < 32) {
            float rs = 0.f;
#pragma unroll
            for (int jj = 0; jj < 32; ++jj) rs += Es[tid][jj];
            lrun[tid] += rs;
        }
        // PV accumulate: thread (i8,dpv) owns rows i8*8..i8*8+7, column dpv
#pragma unroll
        for (int ii = 0; ii < 8; ++ii) {
            const int i = (i8 << 3) + ii;
            float a = 0.f;
#pragma unroll
            for (int jj = 0; jj < 32; ++jj)
                a += Es[i][jj] * Vs[jj][dpv];
            acc[ii] += a;
        }
    }
    __syncthreads();

    // out[b, l, h*64+d] = acc / (EPS + rowsum)
#pragma unroll
    for (int ii = 0; ii < 8; ++ii) {
        const int i = (i8 << 3) + ii;
        out[((size_t)(b * SS + (l0 + i)) * HHID) + hh * DD + dpv]
            = acc[ii] / (EPSV + lrun[i]);
    }
}

// ---------------------------------------------------------------------------
extern "C" void kernel_launch(void* const* d_in, const int* in_sizes, int n_in,
                              void* d_out, int out_size, void* d_ws, size_t ws_size,
                              hipStream_t stream) {
    const float* hidden = (const float*)d_in[0];
    const float* amask  = (const float*)d_in[1];
    const int*   skim   = (const int*)d_in[2];
    const float* Wq     = (const float*)d_in[3];
    const float* bq     = (const float*)d_in[4];
    const float* Wk     = (const float*)d_in[5];
    const float* bk     = (const float*)d_in[6];
    const float* Wv     = (const float*)d_in[7];
    const float* bv     = (const float*)d_in[8];
    const float* dist   = (const float*)d_in[9];
    float* out = (float*)d_out;
    float* ws  = (float*)d_ws;   // 48 MB: Q | K | V as [B*H, S, D] fp32

    dim3 g1(64, 16, 3);
    qkv_gemm<<<g1, 256, 0, stream>>>(hidden, Wq, bq, Wk, bk, Wv, bv, ws);

    dim3 g2(SS / 32, BB * HH);
    attn<<<g2, 256, 0, stream>>>(ws, amask, skim, dist, out);
}

// Round 2
// 242.464 us; speedup vs baseline: 4.2817x; 4.2817x over previous
//
#include <hip/hip_runtime.h>
#include <hip/hip_bf16.h>

// BertSelfAttention B=4,S=1024,HID=1024,H=16,D=64,MAXP=1024 — Round 2: bf16 MFMA.
// Pipeline: cvt X/dist -> bf16 | transpose-cvt W | QKV GEMM (32x32x16 MFMA,
// global_load_lds) | V transpose | fused attn (QK + rolling Toeplitz PE-term
// + masked-softmax + PV, all MFMA).
// ws: [0:8M) Xbf (reused as Vt) | [8M:14M) Wt | [14M:14.25M) distbf |
//     [15M:23M) Qf | [23M:31M) Kf | [31M:39M) Vf

#define EPSV 1e-8f

typedef short bfrag __attribute__((ext_vector_type(8)));   // 8 bf16 (A/B frag)
typedef float cfrag __attribute__((ext_vector_type(16)));  // C/D frag 32x32

__device__ __forceinline__ short f2bf(float f) {
    __hip_bfloat16 h = __float2bfloat16(f);
    return *reinterpret_cast<short*>(&h);
}
__device__ __forceinline__ float bf2f(short s) {
    unsigned int u = ((unsigned int)(unsigned short)s) << 16;
    return __builtin_bit_cast(float, u);
}
__device__ __forceinline__ void gl2lds16(const void* g, void* l) {
    __builtin_amdgcn_global_load_lds(
        (const __attribute__((address_space(1))) unsigned int*)g,
        (__attribute__((address_space(3))) unsigned int*)l, 16, 0, 0);
}

// ---------------------------------------------------------------------------
__global__ __launch_bounds__(256) void cvt_bf16(
    const float* __restrict__ src, short* __restrict__ dst, int n4)
{
    int i = blockIdx.x * 256 + threadIdx.x;
    if (i >= n4) return;
    float4 v = ((const float4*)src)[i];
    short4 o;
    o.x = f2bf(v.x); o.y = f2bf(v.y); o.z = f2bf(v.z); o.w = f2bf(v.w);
    ((short4*)dst)[i] = o;
}

// W [1024 k][1024 n] f32 -> Wt [z][1024 n][1024 k] bf16 (transposed)
__global__ __launch_bounds__(256) void cvt_w_t(
    const float* __restrict__ Wq, const float* __restrict__ Wk,
    const float* __restrict__ Wv, short* __restrict__ Wt)
{
    __shared__ float Tl[32][33];
    const float* W = (blockIdx.z == 0) ? Wq : ((blockIdx.z == 1) ? Wk : Wv);
    short* out = Wt + (size_t)blockIdx.z * 1024 * 1024;
    const int t = threadIdx.x;
    const int k0 = blockIdx.x * 32, n0 = blockIdx.y * 32;
    {
        int kl = t >> 3, nl4 = (t & 7) * 4;
        float4 v = *(const float4*)(W + (size_t)(k0 + kl) * 1024 + n0 + nl4);
        Tl[kl][nl4] = v.x; Tl[kl][nl4 + 1] = v.y;
        Tl[kl][nl4 + 2] = v.z; Tl[kl][nl4 + 3] = v.w;
    }
    __syncthreads();
    int nl = t >> 3, kl4 = (t & 7) * 4;
    short4 o;
    o.x = f2bf(Tl[kl4][nl]);     o.y = f2bf(Tl[kl4 + 1][nl]);
    o.z = f2bf(Tl[kl4 + 2][nl]); o.w = f2bf(Tl[kl4 + 3][nl]);
    *(short4*)(out + (size_t)(n0 + nl) * 1024 + k0 + kl4) = o;
}

// ---------------------------------------------------------------------------
// QKV GEMM: [4096,1024]x[1024,1024] -> head-split bf16 [64 bh][1024 s][64 d]
// 128x128 tile, BK=32, 4 waves each 64x64 (2x2 of 32x32 MFMA tiles)
__global__ __launch_bounds__(256) void qkv_mfma(
    const short* __restrict__ Xbf, const short* __restrict__ Wt,
    const float* __restrict__ bq, const float* __restrict__ bk,
    const float* __restrict__ bv,
    short* __restrict__ Qf, short* __restrict__ Kf, short* __restrict__ Vf)
{
    __shared__ short As[128 * 32];
    __shared__ short Bs[128 * 32];
    const int z = blockIdx.z;
    const short* W = Wt + (size_t)z * 1024 * 1024;
    const float* bias = (z == 0) ? bq : ((z == 1) ? bk : bv);
    short* out = (z == 0) ? Qf : ((z == 1) ? Kf : Vf);
    const float scale = (z == 0) ? 0.125f : 1.0f;   // fold 1/sqrt(D) into Q

    const int tid = threadIdx.x, lane = tid & 63, wid = tid >> 6;
    const int q2 = lane >> 5, l31 = lane & 31;
    const int wr = wid >> 1, wc = wid & 1;
    const int m0 = blockIdx.x * 128, n0 = blockIdx.y * 128;

    cfrag acc[2][2];
#pragma unroll
    for (int i = 0; i < 2; i++)
#pragma unroll
        for (int j = 0; j < 2; j++)
#pragma unroll
            for (int e = 0; e < 16; e++) acc[i][j][e] = 0.f;

    for (int k0 = 0; k0 < 1024; k0 += 32) {
        __syncthreads();   // prior frag reads complete
#pragma unroll
        for (int p = 0; p < 2; p++) {
            const int ub = wid * 2048 + p * 1024;      // wave-uniform LDS base
            const int off = ub + lane * 16;
            const int r = off >> 6, cb = off & 63;     // As/Bs row 64B each
            gl2lds16((const char*)Xbf + ((size_t)(m0 + r) * 1024 + k0) * 2 + cb,
                     (char*)As + ub);
            gl2lds16((const char*)W + ((size_t)(n0 + r) * 1024 + k0) * 2 + cb,
                     (char*)Bs + ub);
        }
        __syncthreads();   // staged (drains vmcnt)
        bfrag a[2][2], b[2][2];
#pragma unroll
        for (int mt = 0; mt < 2; mt++) {
            const int m = wr * 64 + mt * 32 + l31;
#pragma unroll
            for (int kc = 0; kc < 2; kc++)
                a[mt][kc] = *(const bfrag*)&As[m * 32 + kc * 16 + q2 * 8];
        }
#pragma unroll
        for (int nt = 0; nt < 2; nt++) {
            const int n = wc * 64 + nt * 32 + l31;
#pragma unroll
            for (int kc = 0; kc < 2; kc++)
                b[nt][kc] = *(const bfrag*)&Bs[n * 32 + kc * 16 + q2 * 8];
        }
#pragma unroll
        for (int mt = 0; mt < 2; mt++)
#pragma unroll
            for (int nt = 0; nt < 2; nt++)
#pragma unroll
                for (int kc = 0; kc < 2; kc++)
                    acc[mt][nt] = __builtin_amdgcn_mfma_f32_32x32x16_bf16(
                        a[mt][kc], b[nt][kc], acc[mt][nt], 0, 0, 0);
    }

    // epilogue: +bias, (Q: x0.125), cvt bf16, scatter to [bh][s][d]
#pragma unroll
    for (int nt = 0; nt < 2; nt++) {
        const int c = n0 + wc * 64 + nt * 32 + l31;    // channel
        const float bval = bias[c];
        const int h = c >> 6, d = c & 63;
#pragma unroll
        for (int mt = 0; mt < 2; mt++) {
#pragma unroll
            for (int reg = 0; reg < 16; reg++) {
                const int row = (reg & 3) + 8 * (reg >> 2) + 4 * q2;
                const int tok = m0 + wr * 64 + mt * 32 + row;
                const int bb = tok >> 10, s = tok & 1023;
                const float v = (acc[mt][nt][reg] + bval) * scale;
                out[((size_t)(bb * 16 + h) * 1024 + s) * 64 + d] = f2bf(v);
            }
        }
    }
}

// Vf [bh][1024 s][64 d] -> Vt [bh][64 d][1024 s]
__global__ __launch_bounds__(256) void transpose_v(
    const short* __restrict__ Vf, short* __restrict__ Vt)
{
    __shared__ short Tl[64 * 72];
    const int bh = blockIdx.y, s0 = blockIdx.x * 64, tid = threadIdx.x;
    const short* src = Vf + ((size_t)bh * 1024 + s0) * 64;
#pragma unroll
    for (int p = 0; p < 2; p++) {
        const int off = (p * 256 + tid) * 8;
        const int s = off >> 6, d0 = off & 63;
        *(bfrag*)&Tl[s * 72 + d0] = *(const bfrag*)(src + (size_t)s * 64 + d0);
    }
    __syncthreads();
    short* dst = Vt + (size_t)bh * 64 * 1024 + s0;
#pragma unroll
    for (int p = 0; p < 2; p++) {
        const int off = (p * 256 + tid) * 8;
        const int d = off >> 6, sl0 = off & 63;
        short tmp[8];
#pragma unroll
        for (int j = 0; j < 8; j++) tmp[j] = Tl[(sl0 + j) * 72 + d];
        *(bfrag*)(dst + (size_t)d * 1024 + sl0) = *(bfrag*)tmp;
    }
}

// ---------------------------------------------------------------------------
// Fused attention. grid (16 l-tiles, 64 bh), 256 thr (4 waves, 2x2 over 64x64)
__global__ __launch_bounds__(256) void attn_mfma(
    const short* __restrict__ Qf, const short* __restrict__ Kf,
    const short* __restrict__ Vt, const short* __restrict__ Db,
    const float* __restrict__ amask, const int* __restrict__ skim,
    float* __restrict__ out)
{
    __shared__ short Ks[64 * 64];    // [r][d]
    __shared__ short PEs[64 * 64];   // [dist_row][d]
    __shared__ short Vts[64 * 64];   // [d][r]
    __shared__ short Es[64 * 72];    // [l][r] bf16, stride 72 (16B-aligned)
    __shared__ short Tb[64 * 128];   // rolling T[l][dist&127] bf16
    __shared__ float rsum2[2][64];

    const int tid = threadIdx.x, lane = tid & 63, wid = tid >> 6;
    const int q2 = lane >> 5, l31 = lane & 31;
    const int wr = wid >> 1, wc = wid & 1;
    const int bh = blockIdx.y, b = bh >> 4, h = bh & 15;
    const int l0 = blockIdx.x * 64;

    // Q A-frags once (Q pre-scaled by 1/8): A[m=lane&31][k=q2*8+j], 4 d-chunks
    bfrag qa[4];
    {
        const short* qrow = Qf + ((size_t)bh * 1024 + l0 + wr * 32 + l31) * 64;
#pragma unroll
        for (int c = 0; c < 4; c++)
            qa[c] = *(const bfrag*)(qrow + c * 16 + q2 * 8);
    }
    cfrag oacc;
#pragma unroll
    for (int e = 0; e < 16; e++) oacc[e] = 0.f;
    float esum[16];
#pragma unroll
    for (int e = 0; e < 16; e++) esum[e] = 0.f;

    const char* Kg = (const char*)(Kf + (size_t)bh * 1024 * 64);
    const char* Vg = (const char*)(Vt + (size_t)bh * 64 * 1024);

    auto stagePE = [&](int pe_base) {
        const char* Pg = (const char*)Db + (size_t)(pe_base + 1023) * 128;
#pragma unroll
        for (int p = 0; p < 2; p++) {
            const int ub = wid * 2048 + p * 1024;
            gl2lds16(Pg + ub + lane * 16, (char*)PEs + ub);
        }
    };
    auto Tcompute = [&](int pe_base) {
        cfrag t;
#pragma unroll
        for (int e = 0; e < 16; e++) t[e] = 0.f;
#pragma unroll
        for (int c = 0; c < 4; c++) {
            bfrag pb = *(const bfrag*)&PEs[(wc * 32 + l31) * 64 + c * 16 + q2 * 8];
            t = __builtin_amdgcn_mfma_f32_32x32x16_bf16(qa[c], pb, t, 0, 0, 0);
        }
        const int slot = ((pe_base + wc * 32 + l31) + 2048) & 127;
#pragma unroll
        for (int reg = 0; reg < 16; reg++) {
            const int row = (reg & 3) + 8 * (reg >> 2) + 4 * q2;
            Tb[(wr * 32 + row) * 128 + slot] = f2bf(t[reg]);
        }
    };

    // pre-loop: T for dist [l0-64, l0-1]
    stagePE(l0 - 64);
    __syncthreads();
    Tcompute(l0 - 64);

    for (int r0 = 0; r0 < 1024; r0 += 64) {
        __syncthreads();   // (A) prior reads of Ks/Vts/PEs/Tb done
#pragma unroll
        for (int p = 0; p < 2; p++) {
            const int ub = wid * 2048 + p * 1024;
            const int off = ub + lane * 16;
            gl2lds16(Kg + (size_t)r0 * 128 + off, (char*)Ks + ub);
            const int d = off >> 7, inner = off & 127;
            gl2lds16(Vg + (size_t)d * 2048 + (size_t)r0 * 2 + inner,
                     (char*)Vts + ub);
        }
        const int pe_base = (r0 == 0) ? l0 : (l0 - r0 - 63);
        stagePE(pe_base);
        __syncthreads();   // (B) staged
        Tcompute(pe_base); // new 64 dist columns
        __syncthreads();   // (C) Tb visible

        // scores + masked-softmax numerator
        cfrag sfr;
#pragma unroll
        for (int e = 0; e < 16; e++) sfr[e] = 0.f;
#pragma unroll
        for (int c = 0; c < 4; c++) {
            bfrag kb = *(const bfrag*)&Ks[(wc * 32 + l31) * 64 + c * 16 + q2 * 8];
            sfr = __builtin_amdgcn_mfma_f32_32x32x16_bf16(qa[c], kb, sfr, 0, 0, 0);
        }
        const int r = r0 + wc * 32 + l31;
        const float am = amask[b * 1024 + r];
        const float sk = (float)skim[b * 1024 + r];
#pragma unroll
        for (int reg = 0; reg < 16; reg++) {
            const int row = (reg & 3) + 8 * (reg >> 2) + 4 * q2;
            const int dist = (l0 + wr * 32 + row) - r;
            const float sc = sfr[reg]
                + bf2f(Tb[(wr * 32 + row) * 128 + ((dist + 2048) & 127)]) + am;
            const float e = __expf(sc) * sk;
            const short eb = f2bf(e);
            Es[(wr * 32 + row) * 72 + wc * 32 + l31] = eb;
            esum[reg] += bf2f(eb);   // denom from same rounded values as numer
        }
        __syncthreads();   // (D) Es visible

        // PV: out[l, d-half wc] += E[l, r] * V[r, d]
#pragma unroll
        for (int kc = 0; kc < 4; kc++) {
            bfrag ea = *(const bfrag*)&Es[(wr * 32 + l31) * 72 + kc * 16 + q2 * 8];
            bfrag vb = *(const bfrag*)&Vts[(wc * 32 + l31) * 64 + kc * 16 + q2 * 8];
            oacc = __builtin_amdgcn_mfma_f32_32x32x16_bf16(ea, vb, oacc, 0, 0, 0);
        }
    }

    // row sums: reduce across the 32 cols of this wave, combine wc halves
#pragma unroll
    for (int reg = 0; reg < 16; reg++) {
        float v = esum[reg];
#pragma unroll
        for (int m = 1; m <= 16; m <<= 1) v += __shfl_xor(v, m, 64);
        if (l31 == 0)
            rsum2[wc][wr * 32 + (reg & 3) + 8 * (reg >> 2) + 4 * q2] = v;
    }
    __syncthreads();

    const size_t obase = ((size_t)b * 1024) * 1024 + (size_t)h * 64;
#pragma unroll
    for (int reg = 0; reg < 16; reg++) {
        const int row = (reg & 3) + 8 * (reg >> 2) + 4 * q2;
        const int l = l0 + wr * 32 + row;
        const float denom = EPSV + rsum2[0][wr * 32 + row] + rsum2[1][wr * 32 + row];
        out[obase + (size_t)l * 1024 + wc * 32 + l31] = oacc[reg] / denom;
    }
}

// ---------------------------------------------------------------------------
extern "C" void kernel_launch(void* const* d_in, const int* in_sizes, int n_in,
                              void* d_out, int out_size, void* d_ws, size_t ws_size,
                              hipStream_t stream) {
    const float* hidden = (const float*)d_in[0];
    const float* amask  = (const float*)d_in[1];
    const int*   skim   = (const int*)d_in[2];
    const float* Wq     = (const float*)d_in[3];
    const float* bq     = (const float*)d_in[4];
    const float* Wk     = (const float*)d_in[5];
    const float* bk     = (const float*)d_in[6];
    const float* Wv     = (const float*)d_in[7];
    const float* bv     = (const float*)d_in[8];
    const float* dist   = (const float*)d_in[9];
    float* out = (float*)d_out;

    char* w = (char*)d_ws;
    short* Xbf = (short*)(w);                        // 8 MB (reused as Vt)
    short* Wt  = (short*)(w + ((size_t)8 << 20));    // 6 MB
    short* Db  = (short*)(w + ((size_t)14 << 20));   // 0.25 MB
    short* Qf  = (short*)(w + ((size_t)15 << 20));   // 8 MB
    short* Kf  = (short*)(w + ((size_t)23 << 20));   // 8 MB
    short* Vf  = (short*)(w + ((size_t)31 << 20));   // 8 MB
    short* Vt  = Xbf;                                // after qkv_mfma, Xbf is dead

    cvt_bf16<<<4096, 256, 0, stream>>>(hidden, Xbf, 1048576);
    cvt_bf16<<<128, 256, 0, stream>>>(dist, Db, 32752);
    cvt_w_t<<<dim3(32, 32, 3), 256, 0, stream>>>(Wq, Wk, Wv, Wt);
    qkv_mfma<<<dim3(32, 8, 3), 256, 0, stream>>>(Xbf, Wt, bq, bk, bv, Qf, Kf, Vf);
    transpose_v<<<dim3(16, 64), 256, 0, stream>>>(Vf, Vt);
    attn_mfma<<<dim3(16, 64), 256, 0, stream>>>(Qf, Kf, Vt, Db, amask, skim, out);
}

// Round 3
// 232.459 us; speedup vs baseline: 4.4660x; 1.0430x over previous
//
#include <hip/hip_runtime.h>
#include <hip/hip_bf16.h>

// BertSelfAttention B=4,S=1024,HID=1024,H=16,D=64,MAXP=1024 — Round 3.
// R2 post-mortem: SQ_LDS_BANK_CONFLICT=2.25e7 — 32-way conflicts from
// 128B-stride LDS rows forced by global_load_lds. R3: stage via VGPR +
// ds_write_b128 into PADDED rows (72 shorts attn / 40 shorts gemm) = b128
// conflict floor. Also folds X fp32->bf16 cvt into qkv_mfma.
// ws: [0:8M) Vt | [8M:14M) Wt | [14M:14.25M) distbf | [15M:23M) Qf |
//     [23M:31M) Kf | [31M:39M) Vf

#define EPSV 1e-8f

typedef short bfrag __attribute__((ext_vector_type(8)));   // 8 bf16 (A/B frag)
typedef float cfrag __attribute__((ext_vector_type(16)));  // C/D frag 32x32

__device__ __forceinline__ short f2bf(float f) {
    __hip_bfloat16 h = __float2bfloat16(f);
    return *reinterpret_cast<short*>(&h);
}
__device__ __forceinline__ float bf2f(short s) {
    unsigned int u = ((unsigned int)(unsigned short)s) << 16;
    return __builtin_bit_cast(float, u);
}

// ---------------------------------------------------------------------------
__global__ __launch_bounds__(256) void cvt_bf16(
    const float* __restrict__ src, short* __restrict__ dst, int n4)
{
    int i = blockIdx.x * 256 + threadIdx.x;
    if (i >= n4) return;
    float4 v = ((const float4*)src)[i];
    short4 o;
    o.x = f2bf(v.x); o.y = f2bf(v.y); o.z = f2bf(v.z); o.w = f2bf(v.w);
    ((short4*)dst)[i] = o;
}

// W [1024 k][1024 n] f32 -> Wt [z][1024 n][1024 k] bf16 (transposed)
__global__ __launch_bounds__(256) void cvt_w_t(
    const float* __restrict__ Wq, const float* __restrict__ Wk,
    const float* __restrict__ Wv, short* __restrict__ Wt)
{
    __shared__ float Tl[32][33];
    const float* W = (blockIdx.z == 0) ? Wq : ((blockIdx.z == 1) ? Wk : Wv);
    short* out = Wt + (size_t)blockIdx.z * 1024 * 1024;
    const int t = threadIdx.x;
    const int k0 = blockIdx.x * 32, n0 = blockIdx.y * 32;
    {
        int kl = t >> 3, nl4 = (t & 7) * 4;
        float4 v = *(const float4*)(W + (size_t)(k0 + kl) * 1024 + n0 + nl4);
        Tl[kl][nl4] = v.x; Tl[kl][nl4 + 1] = v.y;
        Tl[kl][nl4 + 2] = v.z; Tl[kl][nl4 + 3] = v.w;
    }
    __syncthreads();
    int nl = t >> 3, kl4 = (t & 7) * 4;
    short4 o;
    o.x = f2bf(Tl[kl4][nl]);     o.y = f2bf(Tl[kl4 + 1][nl]);
    o.z = f2bf(Tl[kl4 + 2][nl]); o.w = f2bf(Tl[kl4 + 3][nl]);
    *(short4*)(out + (size_t)(n0 + nl) * 1024 + k0 + kl4) = o;
}

// ---------------------------------------------------------------------------
// QKV GEMM: X fp32 [4096,1024] x Wt bf16 -> head-split bf16 [64 bh][1024 s][64 d]
// 128x128 tile, BK=32, 4 waves 2x2 of 32x32x16 MFMA. LDS rows padded to 40
// shorts (80 B) -> b128 frag reads at conflict floor.
__global__ __launch_bounds__(256) void qkv_mfma(
    const float* __restrict__ X, const short* __restrict__ Wt,
    const float* __restrict__ bq, const float* __restrict__ bk,
    const float* __restrict__ bv,
    short* __restrict__ Qf, short* __restrict__ Kf, short* __restrict__ Vf)
{
    __shared__ short As[128 * 40];
    __shared__ short Bs[128 * 40];
    const int z = blockIdx.z;
    const short* W = Wt + (size_t)z * 1024 * 1024;
    const float* bias = (z == 0) ? bq : ((z == 1) ? bk : bv);
    short* out = (z == 0) ? Qf : ((z == 1) ? Kf : Vf);
    const float scale = (z == 0) ? 0.125f : 1.0f;   // fold 1/sqrt(D) into Q

    const int tid = threadIdx.x, lane = tid & 63, wid = tid >> 6;
    const int q2 = lane >> 5, l31 = lane & 31;
    const int wr = wid >> 1, wc = wid & 1;
    const int m0 = blockIdx.x * 128, n0 = blockIdx.y * 128;

    cfrag acc[2][2];
#pragma unroll
    for (int i = 0; i < 2; i++)
#pragma unroll
        for (int j = 0; j < 2; j++)
#pragma unroll
            for (int e = 0; e < 16; e++) acc[i][j][e] = 0.f;

    for (int k0 = 0; k0 < 1024; k0 += 32) {
        // global -> VGPR (A: 2x float4x2, B: 2x short8 per thread)
        float4 xa[2][2]; bfrag wbv[2];
#pragma unroll
        for (int p = 0; p < 2; p++) {
            const int chunk = p * 256 + tid;       // 512 chunks of 8 elems
            const int r = chunk >> 2, c8 = (chunk & 3) * 8;
            const float* xp = X + (size_t)(m0 + r) * 1024 + k0 + c8;
            xa[p][0] = *(const float4*)xp;
            xa[p][1] = *(const float4*)(xp + 4);
            wbv[p] = *(const bfrag*)(W + (size_t)(n0 + r) * 1024 + k0 + c8);
        }
        __syncthreads();   // prior frag reads complete
#pragma unroll
        for (int p = 0; p < 2; p++) {
            const int chunk = p * 256 + tid;
            const int r = chunk >> 2, c8 = (chunk & 3) * 8;
            short o[8];
            o[0] = f2bf(xa[p][0].x); o[1] = f2bf(xa[p][0].y);
            o[2] = f2bf(xa[p][0].z); o[3] = f2bf(xa[p][0].w);
            o[4] = f2bf(xa[p][1].x); o[5] = f2bf(xa[p][1].y);
            o[6] = f2bf(xa[p][1].z); o[7] = f2bf(xa[p][1].w);
            *(bfrag*)&As[r * 40 + c8] = *(bfrag*)o;
            *(bfrag*)&Bs[r * 40 + c8] = wbv[p];
        }
        __syncthreads();   // staged

        bfrag a[2][2], b[2][2];
#pragma unroll
        for (int mt = 0; mt < 2; mt++) {
            const int m = wr * 64 + mt * 32 + l31;
#pragma unroll
            for (int kc = 0; kc < 2; kc++)
                a[mt][kc] = *(const bfrag*)&As[m * 40 + kc * 16 + q2 * 8];
        }
#pragma unroll
        for (int nt = 0; nt < 2; nt++) {
            const int n = wc * 64 + nt * 32 + l31;
#pragma unroll
            for (int kc = 0; kc < 2; kc++)
                b[nt][kc] = *(const bfrag*)&Bs[n * 40 + kc * 16 + q2 * 8];
        }
#pragma unroll
        for (int mt = 0; mt < 2; mt++)
#pragma unroll
            for (int nt = 0; nt < 2; nt++)
#pragma unroll
                for (int kc = 0; kc < 2; kc++)
                    acc[mt][nt] = __builtin_amdgcn_mfma_f32_32x32x16_bf16(
                        a[mt][kc], b[nt][kc], acc[mt][nt], 0, 0, 0);
    }

    // epilogue: +bias, (Q: x0.125), cvt bf16, scatter to [bh][s][d]
#pragma unroll
    for (int nt = 0; nt < 2; nt++) {
        const int c = n0 + wc * 64 + nt * 32 + l31;    // channel
        const float bval = bias[c];
        const int h = c >> 6, d = c & 63;
#pragma unroll
        for (int mt = 0; mt < 2; mt++) {
#pragma unroll
            for (int reg = 0; reg < 16; reg++) {
                const int row = (reg & 3) + 8 * (reg >> 2) + 4 * q2;
                const int tok = m0 + wr * 64 + mt * 32 + row;
                const int bb = tok >> 10, s = tok & 1023;
                const float v = (acc[mt][nt][reg] + bval) * scale;
                out[((size_t)(bb * 16 + h) * 1024 + s) * 64 + d] = f2bf(v);
            }
        }
    }
}

// Vf [bh][1024 s][64 d] -> Vt [bh][64 d][1024 s]
__global__ __launch_bounds__(256) void transpose_v(
    const short* __restrict__ Vf, short* __restrict__ Vt)
{
    __shared__ short Tl[64 * 72];
    const int bh = blockIdx.y, s0 = blockIdx.x * 64, tid = threadIdx.x;
    const short* src = Vf + ((size_t)bh * 1024 + s0) * 64;
#pragma unroll
    for (int p = 0; p < 2; p++) {
        const int off = (p * 256 + tid) * 8;
        const int s = off >> 6, d0 = off & 63;
        *(bfrag*)&Tl[s * 72 + d0] = *(const bfrag*)(src + (size_t)s * 64 + d0);
    }
    __syncthreads();
    short* dst = Vt + (size_t)bh * 64 * 1024 + s0;
#pragma unroll
    for (int p = 0; p < 2; p++) {
        const int off = (p * 256 + tid) * 8;
        const int d = off >> 6, sl0 = off & 63;
        short tmp[8];
#pragma unroll
        for (int j = 0; j < 8; j++) tmp[j] = Tl[(sl0 + j) * 72 + d];
        *(bfrag*)(dst + (size_t)d * 1024 + sl0) = *(bfrag*)tmp;
    }
}

// ---------------------------------------------------------------------------
// Fused attention. grid (16 l-tiles, 64 bh), 256 thr (4 waves, 2x2 over 64x64)
// All LDS tiles padded to 72-short rows (144 B) -> conflict-floor b128 reads.
__global__ __launch_bounds__(256) void attn_mfma(
    const short* __restrict__ Qf, const short* __restrict__ Kf,
    const short* __restrict__ Vt, const short* __restrict__ Db,
    const float* __restrict__ amask, const int* __restrict__ skim,
    float* __restrict__ out)
{
    __shared__ short Ks[64 * 72];    // [r][d]
    __shared__ short PEs[64 * 72];   // [dist_row][d]
    __shared__ short Vts[64 * 72];   // [d][r]
    __shared__ short Es[64 * 72];    // [l][r] bf16
    __shared__ short Tb[64 * 128];   // rolling T[l][dist&127] bf16
    __shared__ float rsum2[2][64];

    const int tid = threadIdx.x, lane = tid & 63, wid = tid >> 6;
    const int q2 = lane >> 5, l31 = lane & 31;
    const int wr = wid >> 1, wc = wid & 1;
    const int bh = blockIdx.y, b = bh >> 4, h = bh & 15;
    const int l0 = blockIdx.x * 64;

    const int s_r = tid >> 3;            // staging row 0..31 (x2 phases -> 64)
    const int s_c = (tid & 7) * 8;       // staging col chunk

    // Q A-frags once (Q pre-scaled by 1/8): A[m=lane&31][k=q2*8+j], 4 d-chunks
    bfrag qa[4];
    {
        const short* qrow = Qf + ((size_t)bh * 1024 + l0 + wr * 32 + l31) * 64;
#pragma unroll
        for (int c = 0; c < 4; c++)
            qa[c] = *(const bfrag*)(qrow + c * 16 + q2 * 8);
    }
    cfrag oacc;
#pragma unroll
    for (int e = 0; e < 16; e++) oacc[e] = 0.f;
    float esum[16];
#pragma unroll
    for (int e = 0; e < 16; e++) esum[e] = 0.f;

    const short* Kg = Kf + (size_t)bh * 1024 * 64;
    const short* Vg = Vt + (size_t)bh * 64 * 1024;

    auto Tcompute = [&](int pe_base) {
        cfrag t;
#pragma unroll
        for (int e = 0; e < 16; e++) t[e] = 0.f;
#pragma unroll
        for (int c = 0; c < 4; c++) {
            bfrag pb = *(const bfrag*)&PEs[(wc * 32 + l31) * 72 + c * 16 + q2 * 8];
            t = __builtin_amdgcn_mfma_f32_32x32x16_bf16(qa[c], pb, t, 0, 0, 0);
        }
        const int slot = ((pe_base + wc * 32 + l31) + 2048) & 127;
#pragma unroll
        for (int reg = 0; reg < 16; reg++) {
            const int row = (reg & 3) + 8 * (reg >> 2) + 4 * q2;
            Tb[(wr * 32 + row) * 128 + slot] = f2bf(t[reg]);
        }
    };

    // pre-loop: T for dist [l0-64, l0-1]
    {
        const short* Pg = Db + (size_t)(l0 - 64 + 1023) * 64;
#pragma unroll
        for (int p = 0; p < 2; p++) {
            const int r = p * 32 + s_r;
            *(bfrag*)&PEs[r * 72 + s_c] = *(const bfrag*)(Pg + (size_t)r * 64 + s_c);
        }
    }
    __syncthreads();
    Tcompute(l0 - 64);

    for (int r0 = 0; r0 < 1024; r0 += 64) {
        const int pe_base = (r0 == 0) ? l0 : (l0 - r0 - 63);
        const short* Pg = Db + (size_t)(pe_base + 1023) * 64;
        bfrag kv[2], vv[2], pe[2];
#pragma unroll
        for (int p = 0; p < 2; p++) {
            const int r = p * 32 + s_r;
            kv[p] = *(const bfrag*)(Kg + (size_t)(r0 + r) * 64 + s_c);
            vv[p] = *(const bfrag*)(Vg + (size_t)r * 1024 + r0 + s_c);
            pe[p] = *(const bfrag*)(Pg + (size_t)r * 64 + s_c);
        }
        __syncthreads();   // (A) prior reads of Ks/Vts/PEs/Tb done
#pragma unroll
        for (int p = 0; p < 2; p++) {
            const int r = p * 32 + s_r;
            *(bfrag*)&Ks[r * 72 + s_c]  = kv[p];
            *(bfrag*)&Vts[r * 72 + s_c] = vv[p];
            *(bfrag*)&PEs[r * 72 + s_c] = pe[p];
        }
        __syncthreads();   // (B) staged
        Tcompute(pe_base); // new 64 dist columns
        __syncthreads();   // (C) Tb visible

        // scores + masked-softmax numerator
        cfrag sfr;
#pragma unroll
        for (int e = 0; e < 16; e++) sfr[e] = 0.f;
#pragma unroll
        for (int c = 0; c < 4; c++) {
            bfrag kb = *(const bfrag*)&Ks[(wc * 32 + l31) * 72 + c * 16 + q2 * 8];
            sfr = __builtin_amdgcn_mfma_f32_32x32x16_bf16(qa[c], kb, sfr, 0, 0, 0);
        }
        const int r = r0 + wc * 32 + l31;
        const float am = amask[b * 1024 + r];
        const float sk = (float)skim[b * 1024 + r];
#pragma unroll
        for (int reg = 0; reg < 16; reg++) {
            const int row = (reg & 3) + 8 * (reg >> 2) + 4 * q2;
            const int dist = (l0 + wr * 32 + row) - r;
            const float sc = sfr[reg]
                + bf2f(Tb[(wr * 32 + row) * 128 + ((dist + 2048) & 127)]) + am;
            const float e = __expf(sc) * sk;
            const short eb = f2bf(e);
            Es[(wr * 32 + row) * 72 + wc * 32 + l31] = eb;
            esum[reg] += bf2f(eb);   // denom from same rounded values as numer
        }
        __syncthreads();   // (D) Es visible

        // PV: out[l, d-half wc] += E[l, r] * V[r, d]
#pragma unroll
        for (int kc = 0; kc < 4; kc++) {
            bfrag ea = *(const bfrag*)&Es[(wr * 32 + l31) * 72 + kc * 16 + q2 * 8];
            bfrag vb = *(const bfrag*)&Vts[(wc * 32 + l31) * 72 + kc * 16 + q2 * 8];
            oacc = __builtin_amdgcn_mfma_f32_32x32x16_bf16(ea, vb, oacc, 0, 0, 0);
        }
    }

    // row sums: reduce across the 32 cols of this wave, combine wc halves
#pragma unroll
    for (int reg = 0; reg < 16; reg++) {
        float v = esum[reg];
#pragma unroll
        for (int m = 1; m <= 16; m <<= 1) v += __shfl_xor(v, m, 64);
        if (l31 == 0)
            rsum2[wc][wr * 32 + (reg & 3) + 8 * (reg >> 2) + 4 * q2] = v;
    }
    __syncthreads();

    const size_t obase = ((size_t)b * 1024) * 1024 + (size_t)h * 64;
#pragma unroll
    for (int reg = 0; reg < 16; reg++) {
        const int row = (reg & 3) + 8 * (reg >> 2) + 4 * q2;
        const int l = l0 + wr * 32 + row;
        const float denom = EPSV + rsum2[0][wr * 32 + row] + rsum2[1][wr * 32 + row];
        out[obase + (size_t)l * 1024 + wc * 32 + l31] = oacc[reg] / denom;
    }
}

// ---------------------------------------------------------------------------
extern "C" void kernel_launch(void* const* d_in, const int* in_sizes, int n_in,
                              void* d_out, int out_size, void* d_ws, size_t ws_size,
                              hipStream_t stream) {
    const float* hidden = (const float*)d_in[0];
    const float* amask  = (const float*)d_in[1];
    const int*   skim   = (const int*)d_in[2];
    const float* Wq     = (const float*)d_in[3];
    const float* bq     = (const float*)d_in[4];
    const float* Wk     = (const float*)d_in[5];
    const float* bk     = (const float*)d_in[6];
    const float* Wv     = (const float*)d_in[7];
    const float* bv     = (const float*)d_in[8];
    const float* dist   = (const float*)d_in[9];
    float* out = (float*)d_out;

    char* w = (char*)d_ws;
    short* Vt  = (short*)(w);                        // 8 MB
    short* Wt  = (short*)(w + ((size_t)8 << 20));    // 6 MB
    short* Db  = (short*)(w + ((size_t)14 << 20));   // 0.25 MB
    short* Qf  = (short*)(w + ((size_t)15 << 20));   // 8 MB
    short* Kf  = (short*)(w + ((size_t)23 << 20));   // 8 MB
    short* Vf  = (short*)(w + ((size_t)31 << 20));   // 8 MB

    cvt_bf16<<<128, 256, 0, stream>>>(dist, Db, 32752);
    cvt_w_t<<<dim3(32, 32, 3), 256, 0, stream>>>(Wq, Wk, Wv, Wt);
    qkv_mfma<<<dim3(32, 8, 3), 256, 0, stream>>>(hidden, Wt, bq, bk, bv, Qf, Kf, Vf);
    transpose_v<<<dim3(16, 64), 256, 0, stream>>>(Vf, Vt);
    attn_mfma<<<dim3(16, 64), 256, 0, stream>>>(Qf, Kf, Vt, Db, amask, skim, out);
}